// Round 5
// baseline (322.420 us; speedup 1.0000x reference)
//
#include <hip/hip_runtime.h>
#include <hip/hip_bf16.h>

#define D_MODEL 1024
#define N_HEADS 16
#define D_HEAD  64
#define BATCH   4
#define SEQ     2048
#define LOG2E   1.44269504088896f

typedef __attribute__((ext_vector_type(8))) short short8;
typedef __attribute__((ext_vector_type(8))) unsigned short ushort8;
typedef __attribute__((ext_vector_type(4))) unsigned short ushort4v;
typedef __attribute__((ext_vector_type(4))) float f32x4;

__device__ inline unsigned short f2bf(float f) {
  unsigned int u = __builtin_bit_cast(unsigned int, f);
  u += 0x7fffu + ((u >> 16) & 1u);
  return (unsigned short)(u >> 16);
}

__device__ inline float exp2_fast(float x) {
  return __builtin_amdgcn_exp2f(x);   // v_exp_f32: native 2^x
}

__device__ inline f32x4 mfma_bf16(short8 a, short8 b, f32x4 c) {
  return __builtin_amdgcn_mfma_f32_16x16x32_bf16(a, b, c, 0, 0, 0);
}

// ---------------- fp32 -> bf16 conversion ----------------
__global__ void cvt_kernel(const float* __restrict__ src,
                           unsigned short* __restrict__ dst, int n) {
  int i = (blockIdx.x * 256 + threadIdx.x) * 8;
  if (i >= n) return;
  float4 a = *reinterpret_cast<const float4*>(src + i);
  float4 b = *reinterpret_cast<const float4*>(src + i + 4);
  ushort8 o;
  o[0] = f2bf(a.x); o[1] = f2bf(a.y); o[2] = f2bf(a.z); o[3] = f2bf(a.w);
  o[4] = f2bf(b.x); o[5] = f2bf(b.y); o[6] = f2bf(b.z); o[7] = f2bf(b.w);
  *reinterpret_cast<ushort8*>(dst + i) = o;
}

// ---------------- swizzled global->LDS staging ----------------
template<int NBYTES>
__device__ inline void stage_swz(const unsigned short* g0, int g_stride_elems,
                                 unsigned short* lds0, int tid) {
#pragma unroll
  for (int it = 0; it < NBYTES / 4096; ++it) {
    int o = it * 4096 + tid * 16;
    int r = o >> 7;
    int cb = (o & 127) ^ ((r & 7) << 4);
    unsigned short* g = const_cast<unsigned short*>(g0) +
                        (size_t)r * g_stride_elems + (cb >> 1);
    unsigned short* l = lds0 + (o >> 1);
    __builtin_amdgcn_global_load_lds((__attribute__((address_space(1))) void*)g,
                                     (__attribute__((address_space(3))) void*)l,
                                     16, 0, 0);
  }
}

// swizzled LDS fragment read (16B): row-stride fixed 128B
__device__ inline short8 frag_ld(const unsigned short* tile, int row, int col_el) {
  int cb = (col_el << 1) ^ ((row & 7) << 4);
  return *reinterpret_cast<const short8*>(
      reinterpret_cast<const char*>(tile) + row * 128 + cb);
}

// ---------------- QKV projection GEMM ----------------
// z=0 -> Q scaled by 0.125*log2e (exp2-domain softmax), z=1 -> K, z=2 -> V^T
__launch_bounds__(256, 2)
__global__ void qkv_gemm(const unsigned short* __restrict__ xb,
                         const unsigned short* __restrict__ wb,
                         unsigned short* __restrict__ Qo,
                         unsigned short* __restrict__ Ko,
                         unsigned short* __restrict__ Vt) {
  __shared__ __align__(16) unsigned short As[128][64];
  __shared__ __align__(16) unsigned short Bs[128][64];
  const int z = blockIdx.z;
  const int m0 = blockIdx.y * 128;
  const int n0 = blockIdx.x * 128;
  const int tid = threadIdx.x;
  const int lane = tid & 63;
  const int wv = tid >> 6;
  const int wr = wv >> 1, wc = wv & 1;
  const int lrow = lane & 15;
  const int lk8 = (lane >> 4) << 3;
  const unsigned short* w = wb + (size_t)z * D_MODEL * D_MODEL;

  f32x4 acc[4][4];
  const f32x4 zero = {0.f, 0.f, 0.f, 0.f};
#pragma unroll
  for (int i = 0; i < 4; ++i)
#pragma unroll
    for (int j = 0; j < 4; ++j) acc[i][j] = zero;

  for (int k0 = 0; k0 < D_MODEL; k0 += 64) {
    __syncthreads();
    stage_swz<16384>(xb + (size_t)m0 * D_MODEL + k0, D_MODEL, &As[0][0], tid);
    stage_swz<16384>(w  + (size_t)n0 * D_MODEL + k0, D_MODEL, &Bs[0][0], tid);
    __syncthreads();
#pragma unroll
    for (int ks = 0; ks < 2; ++ks) {
      short8 af[4], bfr[4];
#pragma unroll
      for (int mi = 0; mi < 4; ++mi)
        af[mi] = frag_ld(&As[0][0], wr * 64 + mi * 16 + lrow, ks * 32 + lk8);
#pragma unroll
      for (int ni = 0; ni < 4; ++ni)
        bfr[ni] = frag_ld(&Bs[0][0], wc * 64 + ni * 16 + lrow, ks * 32 + lk8);
      if (z != 2) {
#pragma unroll
        for (int mi = 0; mi < 4; ++mi)
#pragma unroll
          for (int ni = 0; ni < 4; ++ni)
            acc[mi][ni] = mfma_bf16(af[mi], bfr[ni], acc[mi][ni]);
      } else {
#pragma unroll
        for (int ni = 0; ni < 4; ++ni)
#pragma unroll
          for (int mi = 0; mi < 4; ++mi)
            acc[ni][mi] = mfma_bf16(bfr[ni], af[mi], acc[ni][mi]);
      }
    }
  }

  const int lrr = (lane >> 4) << 2;
  if (z != 2) {
    unsigned short* dst = (z == 0) ? Qo : Ko;
    const float scale = (z == 0) ? 0.125f * LOG2E : 1.0f;
#pragma unroll
    for (int mi = 0; mi < 4; ++mi)
#pragma unroll
      for (int ni = 0; ni < 4; ++ni)
#pragma unroll
        for (int r = 0; r < 4; ++r) {
          int m = m0 + wr * 64 + mi * 16 + lrr + r;
          int e = n0 + wc * 64 + ni * 16 + lrow;
          int b = m >> 11, s = m & (SEQ - 1);
          int h = e >> 6, dh = e & 63;
          dst[((size_t)(b * N_HEADS + h) * SEQ + s) * D_HEAD + dh] =
              f2bf(acc[mi][ni][r] * scale);
        }
  } else {
#pragma unroll
    for (int ni = 0; ni < 4; ++ni)
#pragma unroll
      for (int mi = 0; mi < 4; ++mi)
#pragma unroll
        for (int r = 0; r < 4; ++r) {
          int e = n0 + wc * 64 + ni * 16 + lrr + r;
          int m = m0 + wr * 64 + mi * 16 + lrow;
          int b = m >> 11, s = m & (SEQ - 1);
          int h = e >> 6, dh = e & 63;
          Vt[((size_t)(b * N_HEADS + h) * D_HEAD + dh) * SEQ + s] =
              f2bf(acc[ni][mi][r]);
        }
  }
}

// ---------------- flash attention, 2 batches per block ----------------
// Grid 1024 blocks (32 q-tiles x 16 heads x 2 batch-groups), 3 blocks/CU.
// bg-twin blocks (same h,q-tile) are at adjacent linear ids -> same XCD,
// concurrent -> twin's bias reads hit L2. Bias enters via MFMA C-init;
// softmax in exp2 domain (Q pre-scaled by log2e); defer-max skips rescale.
__launch_bounds__(256, 3)
__global__ void attn_kernel(const unsigned short* __restrict__ Q,
                            const unsigned short* __restrict__ K,
                            const unsigned short* __restrict__ Vt,
                            const float* __restrict__ bias,
                            unsigned short* __restrict__ ctx) {
  __shared__ __align__(16) unsigned short Qs[64][64];
  __shared__ __align__(16) unsigned short Ks[2][64][64];
  __shared__ __align__(16) unsigned short Vs[2][64][64];
  __shared__ __align__(16) unsigned short Ps[4][16][72];

  const int lid = blockIdx.x + 32 * blockIdx.y + 512 * blockIdx.z;
  const int xg = lid & 7, g = lid >> 3;
  const int bg = g & 1;                       // batch-group: twin blocks adjacent
  const int h = (xg << 1) | ((g >> 1) & 1);   // 2 heads per XCD slot
  const int q0 = ((g >> 2) & 31) << 6;

  const int tid = threadIdx.x, lane = tid & 63, wv = tid >> 6;
  const int lrow = lane & 15;
  const int lgrp = lane >> 4;
  const int lk8 = lgrp << 3;
  const int lrr = lgrp << 2;

  // per-batch Q fragments (staged sequentially through one LDS buffer)
  short8 qf[2][2];
#pragma unroll
  for (int b = 0; b < 2; ++b) {
    const int bb = bg * 2 + b;
    stage_swz<8192>(Q + ((size_t)(bb * N_HEADS + h) * SEQ + q0) * D_HEAD,
                    D_HEAD, &Qs[0][0], tid);
    __syncthreads();
#pragma unroll
    for (int ks = 0; ks < 2; ++ks)
      qf[b][ks] = frag_ld(&Qs[0][0], wv * 16 + lrow, ks * 32 + lk8);
    __syncthreads();
  }

  // stage first step (kt=0, b=0)
  stage_swz<8192>(K + (size_t)(bg * 2 * N_HEADS + h) * SEQ * D_HEAD, D_HEAD,
                  &Ks[0][0][0], tid);
  stage_swz<8192>(Vt + (size_t)(bg * 2 * N_HEADS + h) * D_HEAD * SEQ, SEQ,
                  &Vs[0][0][0], tid);

  // bias: per lane q = q0+wv*16+lrow, k = kt*64 + nt*16 + lrr + {0..3}
  const float* bp = bias + (size_t)h * SEQ * SEQ +
                    (size_t)(q0 + wv * 16 + lrow) * SEQ + lrr;
  f32x4 bcur[4], bnext[4];
#pragma unroll
  for (int nt = 0; nt < 4; ++nt)
    bcur[nt] = *reinterpret_cast<const f32x4*>(bp + nt * 16) * LOG2E;

  float m_run[2], l_run[2];
  f32x4 o_acc[2][4];
  const f32x4 zero = {0.f, 0.f, 0.f, 0.f};
#pragma unroll
  for (int b = 0; b < 2; ++b) {
    m_run[b] = -1e30f; l_run[b] = 0.f;
#pragma unroll
    for (int dt = 0; dt < 4; ++dt) o_acc[b][dt] = zero;
  }

  __syncthreads();

  for (int kt = 0; kt < 32; ++kt) {
    // prefetch next kv-tile's bias (shared by both batches), scale to log2e
    if (kt < 31) {
#pragma unroll
      for (int nt = 0; nt < 4; ++nt)
        bnext[nt] = *reinterpret_cast<const f32x4*>(bp + (kt + 1) * 64 +
                                                    nt * 16) * LOG2E;
    }

#pragma unroll
    for (int b = 0; b < 2; ++b) {
      const int cur = b;  // 2 steps per kt -> parity == b

      // stage next step's K/V early (hides under this step's compute)
      if (!(kt == 31 && b == 1)) {
        const int nb = bg * 2 + (b ^ 1);
        const int nkt = kt + b;
        stage_swz<8192>(K + (size_t)(nb * N_HEADS + h) * SEQ * D_HEAD +
                            (size_t)nkt * 64 * D_HEAD,
                        D_HEAD, &Ks[cur ^ 1][0][0], tid);
        stage_swz<8192>(Vt + (size_t)(nb * N_HEADS + h) * D_HEAD * SEQ +
                            nkt * 64,
                        SEQ, &Vs[cur ^ 1][0][0], tid);
      }

      // QK^T (swapped), bias as C-init: lane holds S[k=nt*16+lrr+r][q=lrow]
      f32x4 s[4];
#pragma unroll
      for (int nt = 0; nt < 4; ++nt) s[nt] = bcur[nt];
      __builtin_amdgcn_s_setprio(1);
#pragma unroll
      for (int ks = 0; ks < 2; ++ks)
#pragma unroll
        for (int nt = 0; nt < 4; ++nt) {
          short8 kf = frag_ld(&Ks[cur][0][0], nt * 16 + lrow, ks * 32 + lk8);
          s[nt] = mfma_bf16(kf, qf[b][ks], s[nt]);
        }
      __builtin_amdgcn_s_setprio(0);

      // online softmax (exp2 domain), defer-max
      float pmax =
          fmaxf(fmaxf(fmaxf(fmaxf(s[0][0], s[0][1]), s[0][2]),
                      fmaxf(fmaxf(s[1][0], s[1][1]), s[1][2])),
                fmaxf(fmaxf(fmaxf(s[2][0], s[2][1]), s[2][2]),
                      fmaxf(fmaxf(fmaxf(s[3][0], s[3][1]), s[3][2]),
                            fmaxf(fmaxf(s[0][3], s[1][3]),
                                  fmaxf(s[2][3], s[3][3])))));
      pmax = fmaxf(pmax, __shfl_xor(pmax, 16));
      pmax = fmaxf(pmax, __shfl_xor(pmax, 32));

      if (!__all(pmax - m_run[b] <= 11.0f)) {
        float mnew = fmaxf(m_run[b], pmax);
        float corr = exp2_fast(m_run[b] - mnew);
        l_run[b] *= corr;
        m_run[b] = mnew;
#pragma unroll
        for (int r = 0; r < 4; ++r) {
          float c = __shfl(corr, lrr + r);
#pragma unroll
          for (int dt = 0; dt < 4; ++dt) o_acc[b][dt][r] *= c;
        }
      }

      float p[4][4];
      float rs = 0.f;
#pragma unroll
      for (int nt = 0; nt < 4; ++nt)
#pragma unroll
        for (int r = 0; r < 4; ++r) {
          float e = exp2_fast(s[nt][r] - m_run[b]);
          p[nt][r] = e;
          rs += e;
        }
      rs += __shfl_xor(rs, 16);
      rs += __shfl_xor(rs, 32);
      l_run[b] += rs;

      // P -> LDS (wave-private, native bf16 cvt, 8B packed stores)
#pragma unroll
      for (int nt = 0; nt < 4; ++nt) {
        ushort4v pk;
#pragma unroll
        for (int r = 0; r < 4; ++r)
          pk[r] = __builtin_bit_cast(unsigned short,
                                     __float2bfloat16(p[nt][r]));
        *reinterpret_cast<ushort4v*>(&Ps[wv][lrow][nt * 16 + lrr]) = pk;
      }

      // PV: A = P rows (q = lrow), B = Vt rows (d)
      short8 pf[2];
#pragma unroll
      for (int ks = 0; ks < 2; ++ks)
        pf[ks] = *reinterpret_cast<const short8*>(&Ps[wv][lrow][ks * 32 + lk8]);
      __builtin_amdgcn_s_setprio(1);
#pragma unroll
      for (int ks = 0; ks < 2; ++ks)
#pragma unroll
        for (int dt = 0; dt < 4; ++dt) {
          short8 vf = frag_ld(&Vs[cur][0][0], dt * 16 + lrow, ks * 32 + lk8);
          o_acc[b][dt] = mfma_bf16(pf[ks], vf, o_acc[b][dt]);
        }
      __builtin_amdgcn_s_setprio(0);

      __syncthreads();  // drains this wave's staging DMA + swaps buffers
    }

    if (kt < 31) {
#pragma unroll
      for (int nt = 0; nt < 4; ++nt) bcur[nt] = bnext[nt];
    }
  }

  // epilogue: normalize and store ctx [B,S,D_MODEL]
#pragma unroll
  for (int b = 0; b < 2; ++b) {
    const int bb = bg * 2 + b;
    float inv = 1.0f / l_run[b];
#pragma unroll
    for (int r = 0; r < 4; ++r) {
      float invq = __shfl(inv, lrr + r);
      int qs = q0 + wv * 16 + lrr + r;
#pragma unroll
      for (int dt = 0; dt < 4; ++dt)
        ctx[((size_t)bb * SEQ + qs) * D_MODEL + h * 64 + dt * 16 + lrow] =
            f2bf(o_acc[b][dt][r] * invq);
    }
  }
}

// ---------------- output projection GEMM (+bias, fp32 out) ----------------
__launch_bounds__(256, 2)
__global__ void out_gemm(const unsigned short* __restrict__ cb,
                         const unsigned short* __restrict__ wo,
                         const float* __restrict__ bo,
                         float* __restrict__ out) {
  __shared__ __align__(16) unsigned short As[128][64];
  __shared__ __align__(16) unsigned short Bs[128][64];
  const int m0 = blockIdx.y * 128;
  const int n0 = blockIdx.x * 128;
  const int tid = threadIdx.x;
  const int lane = tid & 63;
  const int wv = tid >> 6;
  const int wr = wv >> 1, wc = wv & 1;
  const int lrow = lane & 15;
  const int lk8 = (lane >> 4) << 3;

  f32x4 acc[4][4];
  const f32x4 zero = {0.f, 0.f, 0.f, 0.f};
#pragma unroll
  for (int i = 0; i < 4; ++i)
#pragma unroll
    for (int j = 0; j < 4; ++j) acc[i][j] = zero;

  for (int k0 = 0; k0 < D_MODEL; k0 += 64) {
    __syncthreads();
    stage_swz<16384>(cb + (size_t)m0 * D_MODEL + k0, D_MODEL, &As[0][0], tid);
    stage_swz<16384>(wo + (size_t)n0 * D_MODEL + k0, D_MODEL, &Bs[0][0], tid);
    __syncthreads();
#pragma unroll
    for (int ks = 0; ks < 2; ++ks) {
      short8 af[4], bfr[4];
#pragma unroll
      for (int mi = 0; mi < 4; ++mi)
        af[mi] = frag_ld(&As[0][0], wr * 64 + mi * 16 + lrow, ks * 32 + lk8);
#pragma unroll
      for (int ni = 0; ni < 4; ++ni)
        bfr[ni] = frag_ld(&Bs[0][0], wc * 64 + ni * 16 + lrow, ks * 32 + lk8);
#pragma unroll
      for (int mi = 0; mi < 4; ++mi)
#pragma unroll
        for (int ni = 0; ni < 4; ++ni)
          acc[mi][ni] = mfma_bf16(af[mi], bfr[ni], acc[mi][ni]);
    }
  }

  const int lrr = (lane >> 4) << 2;
#pragma unroll
  for (int mi = 0; mi < 4; ++mi)
#pragma unroll
    for (int ni = 0; ni < 4; ++ni)
#pragma unroll
      for (int r = 0; r < 4; ++r) {
        int m = m0 + wr * 64 + mi * 16 + lrr + r;
        int e = n0 + wc * 64 + ni * 16 + lrow;
        out[(size_t)m * D_MODEL + e] = acc[mi][ni][r] + bo[e];
      }
}

extern "C" void kernel_launch(void* const* d_in, const int* in_sizes, int n_in,
                              void* d_out, int out_size, void* d_ws, size_t ws_size,
                              hipStream_t stream) {
  const float* x    = (const float*)d_in[0];
  const float* bias = (const float*)d_in[1];
  const float* w_q  = (const float*)d_in[2];
  const float* w_k  = (const float*)d_in[3];
  const float* w_v  = (const float*)d_in[4];
  const float* w_o  = (const float*)d_in[5];
  const float* b_o  = (const float*)d_in[6];
  float* out = (float*)d_out;

  const size_t NX = (size_t)BATCH * SEQ * D_MODEL;       // 8388608
  const size_t NW = (size_t)D_MODEL * D_MODEL;           // 1048576

  unsigned short* xb    = (unsigned short*)d_ws;
  unsigned short* wqkvb = xb + NX;
  unsigned short* wob   = wqkvb + 3 * NW;
  unsigned short* Qb    = wob + NW;
  unsigned short* Kb    = Qb + NX;
  unsigned short* Vtb   = Kb + NX;
  unsigned short* ctxb  = Vtb + NX;

  cvt_kernel<<<(int)(NX / 2048), 256, 0, stream>>>(x, xb, (int)NX);
  cvt_kernel<<<(int)(NW / 2048), 256, 0, stream>>>(w_q, wqkvb, (int)NW);
  cvt_kernel<<<(int)(NW / 2048), 256, 0, stream>>>(w_k, wqkvb + NW, (int)NW);
  cvt_kernel<<<(int)(NW / 2048), 256, 0, stream>>>(w_v, wqkvb + 2 * NW, (int)NW);
  cvt_kernel<<<(int)(NW / 2048), 256, 0, stream>>>(w_o, wob, (int)NW);

  qkv_gemm<<<dim3(8, 64, 3), 256, 0, stream>>>(xb, wqkvb, Qb, Kb, Vtb);
  attn_kernel<<<dim3(32, 16, 2), 256, 0, stream>>>(Qb, Kb, Vtb, bias, ctxb);
  out_gemm<<<dim3(8, 64), 256, 0, stream>>>(ctxb, wob, b_o, out);
}

// Round 6
// 319.782 us; speedup vs baseline: 1.0083x; 1.0083x over previous
//
#include <hip/hip_runtime.h>
#include <hip/hip_bf16.h>

#define D_MODEL 1024
#define N_HEADS 16
#define D_HEAD  64
#define BATCH   4
#define SEQ     2048
#define LOG2E   1.44269504088896f

typedef __attribute__((ext_vector_type(8))) short short8;
typedef __attribute__((ext_vector_type(8))) unsigned short ushort8;
typedef __attribute__((ext_vector_type(4))) unsigned short ushort4v;
typedef __attribute__((ext_vector_type(4))) float f32x4;

__device__ inline unsigned short f2bf(float f) {
  unsigned int u = __builtin_bit_cast(unsigned int, f);
  u += 0x7fffu + ((u >> 16) & 1u);
  return (unsigned short)(u >> 16);
}

__device__ inline float exp2_fast(float x) {
  return __builtin_amdgcn_exp2f(x);   // v_exp_f32: native 2^x
}

__device__ inline f32x4 mfma_bf16(short8 a, short8 b, f32x4 c) {
  return __builtin_amdgcn_mfma_f32_16x16x32_bf16(a, b, c, 0, 0, 0);
}

// ---------------- fp32 -> bf16 conversion ----------------
__global__ void cvt_kernel(const float* __restrict__ src,
                           unsigned short* __restrict__ dst, int n) {
  int i = (blockIdx.x * 256 + threadIdx.x) * 8;
  if (i >= n) return;
  float4 a = *reinterpret_cast<const float4*>(src + i);
  float4 b = *reinterpret_cast<const float4*>(src + i + 4);
  ushort8 o;
  o[0] = f2bf(a.x); o[1] = f2bf(a.y); o[2] = f2bf(a.z); o[3] = f2bf(a.w);
  o[4] = f2bf(b.x); o[5] = f2bf(b.y); o[6] = f2bf(b.z); o[7] = f2bf(b.w);
  *reinterpret_cast<ushort8*>(dst + i) = o;
}

// ---------------- swizzled global->LDS staging ----------------
template<int NBYTES>
__device__ inline void stage_swz(const unsigned short* g0, int g_stride_elems,
                                 unsigned short* lds0, int tid) {
#pragma unroll
  for (int it = 0; it < NBYTES / 4096; ++it) {
    int o = it * 4096 + tid * 16;
    int r = o >> 7;
    int cb = (o & 127) ^ ((r & 7) << 4);
    unsigned short* g = const_cast<unsigned short*>(g0) +
                        (size_t)r * g_stride_elems + (cb >> 1);
    unsigned short* l = lds0 + (o >> 1);
    __builtin_amdgcn_global_load_lds((__attribute__((address_space(1))) void*)g,
                                     (__attribute__((address_space(3))) void*)l,
                                     16, 0, 0);
  }
}

// swizzled LDS fragment read (16B): row-stride fixed 128B
__device__ inline short8 frag_ld(const unsigned short* tile, int row, int col_el) {
  int cb = (col_el << 1) ^ ((row & 7) << 4);
  return *reinterpret_cast<const short8*>(
      reinterpret_cast<const char*>(tile) + row * 128 + cb);
}

// ---------------- QKV projection GEMM ----------------
// z=0 -> Q scaled by 0.125*log2e (exp2-domain softmax), z=1 -> K, z=2 -> V^T
__launch_bounds__(256, 2)
__global__ void qkv_gemm(const unsigned short* __restrict__ xb,
                         const unsigned short* __restrict__ wb,
                         unsigned short* __restrict__ Qo,
                         unsigned short* __restrict__ Ko,
                         unsigned short* __restrict__ Vt) {
  __shared__ __align__(16) unsigned short As[128][64];
  __shared__ __align__(16) unsigned short Bs[128][64];
  const int z = blockIdx.z;
  const int m0 = blockIdx.y * 128;
  const int n0 = blockIdx.x * 128;
  const int tid = threadIdx.x;
  const int lane = tid & 63;
  const int wv = tid >> 6;
  const int wr = wv >> 1, wc = wv & 1;
  const int lrow = lane & 15;
  const int lk8 = (lane >> 4) << 3;
  const unsigned short* w = wb + (size_t)z * D_MODEL * D_MODEL;

  f32x4 acc[4][4];
  const f32x4 zero = {0.f, 0.f, 0.f, 0.f};
#pragma unroll
  for (int i = 0; i < 4; ++i)
#pragma unroll
    for (int j = 0; j < 4; ++j) acc[i][j] = zero;

  for (int k0 = 0; k0 < D_MODEL; k0 += 64) {
    __syncthreads();
    stage_swz<16384>(xb + (size_t)m0 * D_MODEL + k0, D_MODEL, &As[0][0], tid);
    stage_swz<16384>(w  + (size_t)n0 * D_MODEL + k0, D_MODEL, &Bs[0][0], tid);
    __syncthreads();
#pragma unroll
    for (int ks = 0; ks < 2; ++ks) {
      short8 af[4], bfr[4];
#pragma unroll
      for (int mi = 0; mi < 4; ++mi)
        af[mi] = frag_ld(&As[0][0], wr * 64 + mi * 16 + lrow, ks * 32 + lk8);
#pragma unroll
      for (int ni = 0; ni < 4; ++ni)
        bfr[ni] = frag_ld(&Bs[0][0], wc * 64 + ni * 16 + lrow, ks * 32 + lk8);
      if (z != 2) {
#pragma unroll
        for (int mi = 0; mi < 4; ++mi)
#pragma unroll
          for (int ni = 0; ni < 4; ++ni)
            acc[mi][ni] = mfma_bf16(af[mi], bfr[ni], acc[mi][ni]);
      } else {
#pragma unroll
        for (int ni = 0; ni < 4; ++ni)
#pragma unroll
          for (int mi = 0; mi < 4; ++mi)
            acc[ni][mi] = mfma_bf16(bfr[ni], af[mi], acc[ni][mi]);
      }
    }
  }

  const int lrr = (lane >> 4) << 2;
  if (z != 2) {
    unsigned short* dst = (z == 0) ? Qo : Ko;
    const float scale = (z == 0) ? 0.125f * LOG2E : 1.0f;
#pragma unroll
    for (int mi = 0; mi < 4; ++mi)
#pragma unroll
      for (int ni = 0; ni < 4; ++ni)
#pragma unroll
        for (int r = 0; r < 4; ++r) {
          int m = m0 + wr * 64 + mi * 16 + lrr + r;
          int e = n0 + wc * 64 + ni * 16 + lrow;
          int b = m >> 11, s = m & (SEQ - 1);
          int h = e >> 6, dh = e & 63;
          dst[((size_t)(b * N_HEADS + h) * SEQ + s) * D_HEAD + dh] =
              f2bf(acc[mi][ni][r] * scale);
        }
  } else {
#pragma unroll
    for (int ni = 0; ni < 4; ++ni)
#pragma unroll
      for (int mi = 0; mi < 4; ++mi)
#pragma unroll
        for (int r = 0; r < 4; ++r) {
          int e = n0 + wc * 64 + ni * 16 + lrr + r;
          int m = m0 + wr * 64 + mi * 16 + lrow;
          int b = m >> 11, s = m & (SEQ - 1);
          int h = e >> 6, dh = e & 63;
          Vt[((size_t)(b * N_HEADS + h) * D_HEAD + dh) * SEQ + s] =
              f2bf(acc[ni][mi][r]);
        }
  }
}

// ---------------- per-step attention compute (b is compile-time) ----------
__device__ __forceinline__ void attn_step_compute(
    const unsigned short* Kb, const unsigned short* Vb,
    unsigned short (&PsW)[16][72], const f32x4 (&bcur)[4],
    const short8 (&qfb)[2], f32x4 (&oacc)[4], float& m_run, float& l_run,
    int lrow, int lk8, int lrr) {
  // QK^T (swapped), bias as C-init: lane holds S[k=nt*16+lrr+r][q=lrow]
  f32x4 s[4];
#pragma unroll
  for (int nt = 0; nt < 4; ++nt) s[nt] = bcur[nt];
  __builtin_amdgcn_s_setprio(1);
#pragma unroll
  for (int ks = 0; ks < 2; ++ks)
#pragma unroll
    for (int nt = 0; nt < 4; ++nt) {
      short8 kf = frag_ld(Kb, nt * 16 + lrow, ks * 32 + lk8);
      s[nt] = mfma_bf16(kf, qfb[ks], s[nt]);
    }
  __builtin_amdgcn_s_setprio(0);

  // online softmax (exp2 domain), defer-max
  float pmax =
      fmaxf(fmaxf(fmaxf(fmaxf(s[0][0], s[0][1]), s[0][2]),
                  fmaxf(fmaxf(s[1][0], s[1][1]), s[1][2])),
            fmaxf(fmaxf(fmaxf(s[2][0], s[2][1]), s[2][2]),
                  fmaxf(fmaxf(fmaxf(s[3][0], s[3][1]), s[3][2]),
                        fmaxf(fmaxf(s[0][3], s[1][3]),
                              fmaxf(s[2][3], s[3][3])))));
  pmax = fmaxf(pmax, __shfl_xor(pmax, 16));
  pmax = fmaxf(pmax, __shfl_xor(pmax, 32));

  if (!__all(pmax - m_run <= 11.0f)) {
    float mnew = fmaxf(m_run, pmax);
    float corr = exp2_fast(m_run - mnew);
    l_run *= corr;
    m_run = mnew;
#pragma unroll
    for (int r = 0; r < 4; ++r) {
      float c = __shfl(corr, lrr + r);
#pragma unroll
      for (int dt = 0; dt < 4; ++dt) oacc[dt][r] *= c;
    }
  }

  float rs = 0.f;
#pragma unroll
  for (int nt = 0; nt < 4; ++nt) {
    float p0 = exp2_fast(s[nt][0] - m_run);
    float p1 = exp2_fast(s[nt][1] - m_run);
    float p2 = exp2_fast(s[nt][2] - m_run);
    float p3 = exp2_fast(s[nt][3] - m_run);
    rs += (p0 + p1) + (p2 + p3);
    ushort4v pk;
    pk[0] = __builtin_bit_cast(unsigned short, __float2bfloat16(p0));
    pk[1] = __builtin_bit_cast(unsigned short, __float2bfloat16(p1));
    pk[2] = __builtin_bit_cast(unsigned short, __float2bfloat16(p2));
    pk[3] = __builtin_bit_cast(unsigned short, __float2bfloat16(p3));
    *reinterpret_cast<ushort4v*>(&PsW[lrow][nt * 16 + lrr]) = pk;
  }
  rs += __shfl_xor(rs, 16);
  rs += __shfl_xor(rs, 32);
  l_run += rs;

  // PV: A = P rows (q = lrow), B = Vt rows (d)
  short8 pf[2];
#pragma unroll
  for (int ks = 0; ks < 2; ++ks)
    pf[ks] = *reinterpret_cast<const short8*>(&PsW[lrow][ks * 32 + lk8]);
  __builtin_amdgcn_s_setprio(1);
#pragma unroll
  for (int ks = 0; ks < 2; ++ks)
#pragma unroll
    for (int dt = 0; dt < 4; ++dt) {
      short8 vf = frag_ld(Vb, dt * 16 + lrow, ks * 32 + lk8);
      oacc[dt] = mfma_bf16(pf[ks], vf, oacc[dt]);
    }
  __builtin_amdgcn_s_setprio(0);
}

// ---------------- flash attention, 2 batches per block ----------------
// T3/T4 schedule: 3-deep K/V LDS pipeline (tile staged 2 full steps before
// use), counted s_waitcnt vmcnt(12) (never 0 in the loop) + raw s_barrier
// pair per step. Steady-state in-flight: stage(s+1)[4] + stage(s+2)[4] +
// bias(kt+1)[4] = 12. Q aliased into buffer 2 (prologue-only use).
__launch_bounds__(256, 2)
__global__ void attn_kernel(const unsigned short* __restrict__ Q,
                            const unsigned short* __restrict__ K,
                            const unsigned short* __restrict__ Vt,
                            const float* __restrict__ bias,
                            unsigned short* __restrict__ ctx) {
  __shared__ __align__(16) unsigned short Ks[3][64][64];
  __shared__ __align__(16) unsigned short Vs[3][64][64];
  __shared__ __align__(16) unsigned short Ps[4][16][72];

  const int lid = blockIdx.x + 32 * blockIdx.y + 512 * blockIdx.z;
  const int xg = lid & 7, g = lid >> 3;
  const int bg = g & 1;                       // batch-group: twin blocks adjacent
  const int h = (xg << 1) | ((g >> 1) & 1);   // 2 heads per XCD slot
  const int q0 = ((g >> 2) & 31) << 6;

  const int tid = threadIdx.x, lane = tid & 63, wv = tid >> 6;
  const int lrow = lane & 15;
  const int lgrp = lane >> 4;
  const int lk8 = lgrp << 3;
  const int lrr = lgrp << 2;

  // per-batch Q fragments (staged sequentially through the Ks[2] buffer)
  short8 qf[2][2];
#pragma unroll
  for (int b = 0; b < 2; ++b) {
    const int bb = bg * 2 + b;
    stage_swz<8192>(Q + ((size_t)(bb * N_HEADS + h) * SEQ + q0) * D_HEAD,
                    D_HEAD, &Ks[2][0][0], tid);
    __syncthreads();
#pragma unroll
    for (int ks = 0; ks < 2; ++ks)
      qf[b][ks] = frag_ld(&Ks[2][0][0], wv * 16 + lrow, ks * 32 + lk8);
    __syncthreads();
  }

  // issue: stage(0) -> buf0, bias(0) -> bcur, stage(1) -> buf1
  stage_swz<8192>(K + (size_t)(bg * 2 * N_HEADS + h) * SEQ * D_HEAD, D_HEAD,
                  &Ks[0][0][0], tid);
  stage_swz<8192>(Vt + (size_t)(bg * 2 * N_HEADS + h) * D_HEAD * SEQ, SEQ,
                  &Vs[0][0][0], tid);

  const float* bp = bias + (size_t)h * SEQ * SEQ +
                    (size_t)(q0 + wv * 16 + lrow) * SEQ + lrr;
  f32x4 bcur[4], bnext[4];
#pragma unroll
  for (int nt = 0; nt < 4; ++nt)
    bcur[nt] = *reinterpret_cast<const f32x4*>(bp + nt * 16) * LOG2E;

  stage_swz<8192>(K + (size_t)((bg * 2 + 1) * N_HEADS + h) * SEQ * D_HEAD,
                  D_HEAD, &Ks[1][0][0], tid);
  stage_swz<8192>(Vt + (size_t)((bg * 2 + 1) * N_HEADS + h) * D_HEAD * SEQ,
                  SEQ, &Vs[1][0][0], tid);
  asm volatile("" ::: "memory");

  float m_run[2], l_run[2];
  f32x4 o_acc[2][4];
  const f32x4 zero = {0.f, 0.f, 0.f, 0.f};
#pragma unroll
  for (int b = 0; b < 2; ++b) {
    m_run[b] = -1e30f; l_run[b] = 0.f;
#pragma unroll
    for (int dt = 0; dt < 4; ++dt) o_acc[b][dt] = zero;
  }

  int cur = 0;  // s % 3, s = 2*kt + b

  for (int kt = 0; kt < 31; ++kt) {
#pragma unroll
    for (int b = 0; b < 2; ++b) {
      const int nxt = cur >= 1 ? cur - 1 : cur + 2;  // (cur + 2) % 3
      // issue stage(s+2) = tile (kt+1, b)
      stage_swz<8192>(K + (size_t)((bg * 2 + b) * N_HEADS + h) * SEQ * D_HEAD +
                          (size_t)(kt + 1) * 64 * D_HEAD,
                      D_HEAD, &Ks[nxt][0][0], tid);
      stage_swz<8192>(Vt + (size_t)((bg * 2 + b) * N_HEADS + h) * D_HEAD * SEQ +
                          (kt + 1) * 64,
                      SEQ, &Vs[nxt][0][0], tid);
      if (b == 0) {
        // bias(kt+1) prefetch, shared by both batches; scale to log2e
#pragma unroll
        for (int nt = 0; nt < 4; ++nt)
          bnext[nt] = *reinterpret_cast<const f32x4*>(bp + (kt + 1) * 64 +
                                                      nt * 16) * LOG2E;
      }
      asm volatile("" ::: "memory");
      // wait only for tile s + bias(kt); 12 newer loads stay in flight
      asm volatile("s_waitcnt vmcnt(12)" ::: "memory");
      __builtin_amdgcn_s_barrier();
      asm volatile("" ::: "memory");

      if (b == 0)
        attn_step_compute(&Ks[cur][0][0], &Vs[cur][0][0], Ps[wv], bcur, qf[0],
                          o_acc[0], m_run[0], l_run[0], lrow, lk8, lrr);
      else
        attn_step_compute(&Ks[cur][0][0], &Vs[cur][0][0], Ps[wv], bcur, qf[1],
                          o_acc[1], m_run[1], l_run[1], lrow, lk8, lrr);

      asm volatile("" ::: "memory");
      __builtin_amdgcn_s_barrier();  // all done reading buf before re-stage
      cur = cur >= 2 ? 0 : cur + 1;
    }
#pragma unroll
    for (int nt = 0; nt < 4; ++nt) bcur[nt] = bnext[nt];
  }

  // kt = 31 peeled (no more staging; decreasing waits)
  {
    asm volatile("s_waitcnt vmcnt(4)" ::: "memory");
    __builtin_amdgcn_s_barrier();
    asm volatile("" ::: "memory");
    attn_step_compute(&Ks[cur][0][0], &Vs[cur][0][0], Ps[wv], bcur, qf[0],
                      o_acc[0], m_run[0], l_run[0], lrow, lk8, lrr);
    asm volatile("" ::: "memory");
    __builtin_amdgcn_s_barrier();
    cur = cur >= 2 ? 0 : cur + 1;

    asm volatile("s_waitcnt vmcnt(0)" ::: "memory");
    __builtin_amdgcn_s_barrier();
    asm volatile("" ::: "memory");
    attn_step_compute(&Ks[cur][0][0], &Vs[cur][0][0], Ps[wv], bcur, qf[1],
                      o_acc[1], m_run[1], l_run[1], lrow, lk8, lrr);
  }

  // epilogue: normalize and store ctx [B,S,D_MODEL]
#pragma unroll
  for (int b = 0; b < 2; ++b) {
    const int bb = bg * 2 + b;
    float inv = 1.0f / l_run[b];
#pragma unroll
    for (int r = 0; r < 4; ++r) {
      float invq = __shfl(inv, lrr + r);
      int qs = q0 + wv * 16 + lrr + r;
#pragma unroll
      for (int dt = 0; dt < 4; ++dt)
        ctx[((size_t)bb * SEQ + qs) * D_MODEL + h * 64 + dt * 16 + lrow] =
            f2bf(o_acc[b][dt][r] * invq);
    }
  }
}

// ---------------- output projection GEMM (+bias, fp32 out) ----------------
__launch_bounds__(256, 2)
__global__ void out_gemm(const unsigned short* __restrict__ cb,
                         const unsigned short* __restrict__ wo,
                         const float* __restrict__ bo,
                         float* __restrict__ out) {
  __shared__ __align__(16) unsigned short As[128][64];
  __shared__ __align__(16) unsigned short Bs[128][64];
  const int m0 = blockIdx.y * 128;
  const int n0 = blockIdx.x * 128;
  const int tid = threadIdx.x;
  const int lane = tid & 63;
  const int wv = tid >> 6;
  const int wr = wv >> 1, wc = wv & 1;
  const int lrow = lane & 15;
  const int lk8 = (lane >> 4) << 3;

  f32x4 acc[4][4];
  const f32x4 zero = {0.f, 0.f, 0.f, 0.f};
#pragma unroll
  for (int i = 0; i < 4; ++i)
#pragma unroll
    for (int j = 0; j < 4; ++j) acc[i][j] = zero;

  for (int k0 = 0; k0 < D_MODEL; k0 += 64) {
    __syncthreads();
    stage_swz<16384>(cb + (size_t)m0 * D_MODEL + k0, D_MODEL, &As[0][0], tid);
    stage_swz<16384>(wo + (size_t)n0 * D_MODEL + k0, D_MODEL, &Bs[0][0], tid);
    __syncthreads();
#pragma unroll
    for (int ks = 0; ks < 2; ++ks) {
      short8 af[4], bfr[4];
#pragma unroll
      for (int mi = 0; mi < 4; ++mi)
        af[mi] = frag_ld(&As[0][0], wr * 64 + mi * 16 + lrow, ks * 32 + lk8);
#pragma unroll
      for (int ni = 0; ni < 4; ++ni)
        bfr[ni] = frag_ld(&Bs[0][0], wc * 64 + ni * 16 + lrow, ks * 32 + lk8);
#pragma unroll
      for (int mi = 0; mi < 4; ++mi)
#pragma unroll
        for (int ni = 0; ni < 4; ++ni)
          acc[mi][ni] = mfma_bf16(af[mi], bfr[ni], acc[mi][ni]);
    }
  }

  const int lrr = (lane >> 4) << 2;
#pragma unroll
  for (int mi = 0; mi < 4; ++mi)
#pragma unroll
    for (int ni = 0; ni < 4; ++ni)
#pragma unroll
      for (int r = 0; r < 4; ++r) {
        int m = m0 + wr * 64 + mi * 16 + lrr + r;
        int e = n0 + wc * 64 + ni * 16 + lrow;
        out[(size_t)m * D_MODEL + e] = acc[mi][ni][r] + bo[e];
      }
}

extern "C" void kernel_launch(void* const* d_in, const int* in_sizes, int n_in,
                              void* d_out, int out_size, void* d_ws, size_t ws_size,
                              hipStream_t stream) {
  const float* x    = (const float*)d_in[0];
  const float* bias = (const float*)d_in[1];
  const float* w_q  = (const float*)d_in[2];
  const float* w_k  = (const float*)d_in[3];
  const float* w_v  = (const float*)d_in[4];
  const float* w_o  = (const float*)d_in[5];
  const float* b_o  = (const float*)d_in[6];
  float* out = (float*)d_out;

  const size_t NX = (size_t)BATCH * SEQ * D_MODEL;       // 8388608
  const size_t NW = (size_t)D_MODEL * D_MODEL;           // 1048576

  unsigned short* xb    = (unsigned short*)d_ws;
  unsigned short* wqkvb = xb + NX;
  unsigned short* wob   = wqkvb + 3 * NW;
  unsigned short* Qb    = wob + NW;
  unsigned short* Kb    = Qb + NX;
  unsigned short* Vtb   = Kb + NX;
  unsigned short* ctxb  = Vtb + NX;

  cvt_kernel<<<(int)(NX / 2048), 256, 0, stream>>>(x, xb, (int)NX);
  cvt_kernel<<<(int)(NW / 2048), 256, 0, stream>>>(w_q, wqkvb, (int)NW);
  cvt_kernel<<<(int)(NW / 2048), 256, 0, stream>>>(w_k, wqkvb + NW, (int)NW);
  cvt_kernel<<<(int)(NW / 2048), 256, 0, stream>>>(w_v, wqkvb + 2 * NW, (int)NW);
  cvt_kernel<<<(int)(NW / 2048), 256, 0, stream>>>(w_o, wob, (int)NW);

  qkv_gemm<<<dim3(8, 64, 3), 256, 0, stream>>>(xb, wqkvb, Qb, Kb, Vtb);
  attn_kernel<<<dim3(32, 16, 2), 256, 0, stream>>>(Qb, Kb, Vtb, bias, ctxb);
  out_gemm<<<dim3(8, 64), 256, 0, stream>>>(ctxb, wob, b_o, out);
}